// Round 5
// baseline (94.492 us; speedup 1.0000x reference)
//
#include <hip/hip_runtime.h>
#include <math.h>

// EM-routing class-capsule layer, MI355X (gfx950).
// N=1024 positions; one 256-thread block per position.
// Thread t: c = t&31 (output capsule), ig = t>>5 (0..7) owns i = 4*ig+k.
// Reductions over c: shfl_xor butterflies inside 32-lane groups.
// Per routing iteration only TWO __syncthreads():
//   (1) after writing combined partials [Σrr, Σrr·v, Σrr·v²] (wave-level
//       shfl_xor(32) pre-reduce -> part[4][...]),
//   (2) after the distributed reduce producing miu, log(sigma), 0.5/sigma.
// Sigma via exact identity Σr1(v-mu)^2 = Σr1v^2 - mu^2*(2-s1), s1=rs/(rs+EPS)
// (exact algebra incl. coord channels; fp32 cancellation ~1e-7 << bf16 slack).
// R2 lesson: E-step shift kept bit-faithful: 18*(max_{c,ch} log_p - ln10).

#define CI 32
#define CO 32
#define CH 18
#define NPOS 1024
#define PSTR 38               // partial stride per c: [rs][miu*18][v2*18]+pad
#define MSTR 19               // miu/lsig/inv2 padded stride
#define OUT_ACT (16 * CO)     // 512 activation floats, then pose

constexpr float EPSF = 1e-9f;
constexpr float LN10 = 2.302585092994046f;

__device__ __forceinline__ float bf_max32(float x) {
    #pragma unroll
    for (int m = 16; m >= 1; m >>= 1) x = fmaxf(x, __shfl_xor(x, m));
    return x;
}
__device__ __forceinline__ float bf_sum32(float x) {
    #pragma unroll
    for (int m = 16; m >= 1; m >>= 1) x += __shfl_xor(x, m);
    return x;
}

__global__ __launch_bounds__(256) void caps_em_kernel(
    const float* __restrict__ x,
    const float* __restrict__ w,
    const float* __restrict__ beta_v,
    const float* __restrict__ beta_a,
    const float* __restrict__ coord_add,
    float* __restrict__ out)
{
    const int n  = blockIdx.x;
    const int t  = threadIdx.x;
    const int c  = t & 31;
    const int ig = t >> 5;            // 0..7
    const int wv = t >> 6;            // wave 0..3

    __shared__ float pose[CI][16];
    __shared__ float act_in[CI];
    __shared__ float part[4][CO * PSTR];   // 19456 B combined partials
    __shared__ float miu_s[CO * MSTR];     // normalized miu
    __shared__ float lsig_s[CO * MSTR];    // log(sigma_sq)
    __shared__ float inv2_s[CO * MSTR];    // 0.5 / sigma_sq

    // ---- load pose + activations (coalesced) ----
    const float* xrow = x + n * (CI * 17);
    for (int e = t; e < CI * 17; e += 256) {
        int i = e / 17, k = e % 17;
        float val = xrow[e];
        if (k < 16) pose[i][k] = val;
        else        act_in[i]  = val;
    }
    const float cx = coord_add[(n & 63) * 2 + 0];
    const float cy = coord_add[(n & 63) * 2 + 1];
    __syncthreads();

    // ---- votes: v[k][a*4+d] = sum_b pose[i][a*4+b] * w[i][c][b*4+d] ----
    float v[4][16];
    float a_in[4];
    #pragma unroll
    for (int k = 0; k < 4; ++k) {
        int i = ig * 4 + k;
        a_in[k] = act_in[i];
        float pr[16], wr[16];
        const float4* pp4 = (const float4*)pose[i];
        const float4* wp4 = (const float4*)(w + ((i * CO + c) << 4));
        #pragma unroll
        for (int q = 0; q < 4; ++q) {
            float4 pf = pp4[q];
            pr[q*4+0] = pf.x; pr[q*4+1] = pf.y; pr[q*4+2] = pf.z; pr[q*4+3] = pf.w;
            float4 wf = wp4[q];
            wr[q*4+0] = wf.x; wr[q*4+1] = wf.y; wr[q*4+2] = wf.z; wr[q*4+3] = wf.w;
        }
        #pragma unroll
        for (int a = 0; a < 4; ++a) {
            #pragma unroll
            for (int d = 0; d < 4; ++d) {
                float s = pr[a*4+0] * wr[0*4+d];
                s += pr[a*4+1] * wr[1*4+d];
                s += pr[a*4+2] * wr[2*4+d];
                s += pr[a*4+3] * wr[3*4+d];
                v[k][a*4+d] = s;
            }
        }
    }

    float rr[4];
    float act_c = 0.0f;

    for (int it = 0; it < 3; ++it) {
        if (it > 0) {
            // ---- E-step (exact reference shift), ch-outer ----
            float S[4]  = {0.0f, 0.0f, 0.0f, 0.0f};
            float mx[4] = {-3.0e38f, -3.0e38f, -3.0e38f, -3.0e38f};
            #pragma unroll
            for (int ch = 0; ch < CH; ++ch) {
                float mu   = miu_s[c * MSTR + ch];
                float base = -0.5f * lsig_s[c * MSTR + ch];
                float q    = inv2_s[c * MSTR + ch];
                #pragma unroll
                for (int k = 0; k < 4; ++k) {
                    float vv = (ch == 0) ? cx : ((ch == 1) ? cy : v[k][ch - 2]);
                    float d  = vv - mu;
                    float lp = base - d * d * q;
                    S[k] += lp;
                    mx[k] = fmaxf(mx[k], lp);
                }
            }
            #pragma unroll
            for (int k = 0; k < 4; ++k) {
                float m = bf_max32(mx[k]);          // max over (c,ch) for this i
                float shift = 18.0f * (m - LN10);
                float p  = __expf(S[k] - shift);
                float ap = p * act_c;
                float A  = bf_sum32(ap);            // sum over c
                float invA = 1.0f / (A + EPSF);
                float re = ap * invA;
                float sk = A * invA;                // = sum_c re (reassoc)
                float an = a_in[k];
                rr[k] = re * an / (an * sk + EPSF);
            }
        } else {
            #pragma unroll
            for (int k = 0; k < 4; ++k) {
                float an = a_in[k];
                rr[k] = (1.0f / 32.0f) * an / (an + EPSF);
            }
        }

        // ---- combined partials: [Σrr, Σrr·v, Σrr·v²], xor32 pre-reduced ----
        {
            float* pp = &part[wv][c * PSTR];
            float prr = rr[0] + rr[1] + rr[2] + rr[3];
            float prs = prr + __shfl_xor(prr, 32);
            pp[0] = prs;                        // both halves write same value
            // coord channels (v constant over k)
            float s0 = cx * prr, s1v = cy * prr;
            s0  += __shfl_xor(s0, 32);
            s1v += __shfl_xor(s1v, 32);
            pp[1] = s0;  pp[19] = cx * s0;      // Σrr·cx², exact: cx*(Σrr·cx)
            pp[2] = s1v; pp[20] = cy * s1v;
            #pragma unroll
            for (int ch = 2; ch < CH; ++ch) {
                float s = 0.0f, s2 = 0.0f;
                #pragma unroll
                for (int k = 0; k < 4; ++k) {
                    float rv = rr[k] * v[k][ch - 2];
                    s  += rv;
                    s2 += rv * v[k][ch - 2];
                }
                s  += __shfl_xor(s, 32);
                s2 += __shfl_xor(s2, 32);
                pp[1 + ch]  = s;
                pp[19 + ch] = s2;
            }
        }
        __syncthreads();

        // ---- distributed reduce: rs, miu, sigma, log, 0.5/sigma ----
        float r_sum;
        {
            const int base = c * PSTR;
            float rs = part[0][base] + part[1][base] + part[2][base] + part[3][base];
            r_sum = rs;
            float rsinv = 1.0f / (rs + EPSF);
            float s1 = rs * rsinv;
            float c2 = 2.0f - s1;
            for (int ch = ig; ch < CH; ch += 8) {
                int jm = base + 1 + ch, jv = base + 19 + ch;
                float mu_un = part[0][jm] + part[1][jm] + part[2][jm] + part[3][jm];
                float v2_un = part[0][jv] + part[1][jv] + part[2][jv] + part[3][jv];
                float mu = mu_un * rsinv;
                float sig = fmaxf(v2_un * rsinv - mu * mu * c2, 0.0f) + EPSF;
                miu_s[c * MSTR + ch]  = mu;
                lsig_s[c * MSTR + ch] = __logf(sig);
                inv2_s[c * MSTR + ch] = 0.5f / sig;
            }
        }
        __syncthreads();

        // ---- activation softmax over c (butterflies only) ----
        float logit;
        if (it == 2) {
            float cost = 0.0f;
            #pragma unroll
            for (int ch = 0; ch < CH; ++ch)
                cost += beta_v[c * CH + ch] + 0.5f * lsig_s[c * MSTR + ch];
            logit = 0.03f * (beta_a[c] - cost * r_sum);   // ac_lambda = 0.01*3
        } else {
            logit = r_sum;
        }
        float mxl = bf_max32(logit);
        float ex  = __expf(logit - mxl);
        act_c = ex / bf_sum32(ex);
    }

    // ---- fused spatial mean via atomics into d_out ----
    const float inv64 = 1.0f / 64.0f;
    const int b = n >> 6;
    if (t < CO) atomicAdd(&out[b * CO + t], act_c * inv64);   // t<32 -> c==t
    for (int e = t; e < CO * CH; e += 256) {
        int cc = e / CH, ch = e - cc * CH;
        atomicAdd(&out[OUT_ACT + b * (CO * CH) + e], miu_s[cc * MSTR + ch] * inv64);
    }
}

extern "C" void kernel_launch(void* const* d_in, const int* in_sizes, int n_in,
                              void* d_out, int out_size, void* d_ws, size_t ws_size,
                              hipStream_t stream) {
    const float* x         = (const float*)d_in[0];
    const float* w         = (const float*)d_in[1];
    const float* beta_v    = (const float*)d_in[2];
    const float* beta_a    = (const float*)d_in[3];
    const float* coord_add = (const float*)d_in[4];
    float* out = (float*)d_out;

    hipMemsetAsync(out, 0, (size_t)out_size * sizeof(float), stream);
    caps_em_kernel<<<dim3(NPOS), dim3(256), 0, stream>>>(
        x, w, beta_v, beta_a, coord_add, out);
}

// Round 6
// 90.461 us; speedup vs baseline: 1.0446x; 1.0446x over previous
//
#include <hip/hip_runtime.h>
#include <math.h>

// EM-routing class-capsule layer, MI355X (gfx950).
// N=1024 positions; one 256-thread block per position.
// Thread t: c = t&31 (output capsule), ig = t>>5 (0..7) owns i = 4*ig+k.
// R6 edits vs the passing R5 kernel (VALU/latency trims only, semantics kept):
//   (a) all fp32 divides -> v_rcp_f32 (__builtin_amdgcn_rcpf, ~1ulp; EPS
//       placement identical: x * rcp(y + EPS))
//   (b) 32-lane butterflies: masks 1/2/4/8 via DPP (quad_perm xor1/xor2,
//       row_half_mirror==xor4, row_mirror==xor8 under sub-group uniformity);
//       only mask 16 stays a DS op (shfl_xor)
//   (c) E-step stats packed: {mu, 0.5/sigma} as float2 (stride 38 words/c,
//       2-way bank aliasing = free) + base = -0.5*log(sigma) stored directly
//       (lsig = -2*base exactly for the it==2 cost term)
// R2 lesson preserved: E-step shift is bit-faithful 18*(max_{c,ch} lp - ln10).

#define CI 32
#define CO 32
#define CH 18
#define NPOS 1024
#define PSTR 38               // partial stride per c: [rs][m*18][v2*18]+pad
#define OUT_ACT (16 * CO)     // 512 activation floats, then pose

constexpr float EPSF = 1e-9f;
constexpr float LN10 = 2.302585092994046f;

__device__ __forceinline__ float fast_rcp(float x) {
    return __builtin_amdgcn_rcpf(x);
}

template <int CTRL>
__device__ __forceinline__ float dppf(float x) {
    union { float f; int i; } u; u.f = x;
    u.i = __builtin_amdgcn_update_dpp(u.i, u.i, CTRL, 0xF, 0xF, true);
    return u.f;
}

// sum/max over each 32-lane group (lanes 0-31 and 32-63 independently).
__device__ __forceinline__ float bf_sum32(float x) {
    x += dppf<0xB1>(x);    // quad_perm {1,0,3,2} = xor1
    x += dppf<0x4E>(x);    // quad_perm {2,3,0,1} = xor2
    x += dppf<0x141>(x);   // row_half_mirror == xor4 (quads uniform)
    x += dppf<0x140>(x);   // row_mirror == xor8 (8-groups uniform)
    x += __shfl_xor(x, 16);
    return x;
}
__device__ __forceinline__ float bf_max32(float x) {
    x = fmaxf(x, dppf<0xB1>(x));
    x = fmaxf(x, dppf<0x4E>(x));
    x = fmaxf(x, dppf<0x141>(x));
    x = fmaxf(x, dppf<0x140>(x));
    x = fmaxf(x, __shfl_xor(x, 16));
    return x;
}

__global__ __launch_bounds__(256) void caps_em_kernel(
    const float* __restrict__ x,
    const float* __restrict__ w,
    const float* __restrict__ beta_v,
    const float* __restrict__ beta_a,
    const float* __restrict__ coord_add,
    float* __restrict__ out)
{
    const int n  = blockIdx.x;
    const int t  = threadIdx.x;
    const int c  = t & 31;
    const int ig = t >> 5;            // 0..7
    const int wv = t >> 6;            // wave 0..3

    __shared__ float pose[CI][16];
    __shared__ float act_in[CI];
    __shared__ float part[4][CO * PSTR];   // 19456 B combined partials
    __shared__ float2 muq_s[CO * 19];      // {mu, 0.5/sigma}, stride 19 float2/c
    __shared__ float base_s[CO * 19];      // -0.5*log(sigma), stride 19/c

    // ---- load pose + activations (coalesced) ----
    const float* xrow = x + n * (CI * 17);
    for (int e = t; e < CI * 17; e += 256) {
        int i = e / 17, k = e % 17;
        float val = xrow[e];
        if (k < 16) pose[i][k] = val;
        else        act_in[i]  = val;
    }
    const float cx = coord_add[(n & 63) * 2 + 0];
    const float cy = coord_add[(n & 63) * 2 + 1];
    __syncthreads();

    // ---- votes: v[k][a*4+d] = sum_b pose[i][a*4+b] * w[i][c][b*4+d] ----
    float v[4][16];
    float a_in[4];
    #pragma unroll
    for (int k = 0; k < 4; ++k) {
        int i = ig * 4 + k;
        a_in[k] = act_in[i];
        float pr[16], wr[16];
        const float4* pp4 = (const float4*)pose[i];
        const float4* wp4 = (const float4*)(w + ((i * CO + c) << 4));
        #pragma unroll
        for (int q = 0; q < 4; ++q) {
            float4 pf = pp4[q];
            pr[q*4+0] = pf.x; pr[q*4+1] = pf.y; pr[q*4+2] = pf.z; pr[q*4+3] = pf.w;
            float4 wf = wp4[q];
            wr[q*4+0] = wf.x; wr[q*4+1] = wf.y; wr[q*4+2] = wf.z; wr[q*4+3] = wf.w;
        }
        #pragma unroll
        for (int a = 0; a < 4; ++a) {
            #pragma unroll
            for (int d = 0; d < 4; ++d) {
                float s = pr[a*4+0] * wr[0*4+d];
                s += pr[a*4+1] * wr[1*4+d];
                s += pr[a*4+2] * wr[2*4+d];
                s += pr[a*4+3] * wr[3*4+d];
                v[k][a*4+d] = s;
            }
        }
    }

    float rr[4];
    float act_c = 0.0f;

    for (int it = 0; it < 3; ++it) {
        if (it > 0) {
            // ---- E-step (exact reference shift), ch-outer ----
            float S[4]  = {0.0f, 0.0f, 0.0f, 0.0f};
            float mx[4] = {-3.0e38f, -3.0e38f, -3.0e38f, -3.0e38f};
            const float2* muqc = &muq_s[c * 19];
            const float*  bsc  = &base_s[c * 19];
            #pragma unroll
            for (int ch = 0; ch < CH; ++ch) {
                float2 mq = muqc[ch];
                float  bs = bsc[ch];
                #pragma unroll
                for (int k = 0; k < 4; ++k) {
                    float vv = (ch == 0) ? cx : ((ch == 1) ? cy : v[k][ch - 2]);
                    float d  = vv - mq.x;
                    float lp = bs - d * d * mq.y;
                    S[k] += lp;
                    mx[k] = fmaxf(mx[k], lp);
                }
            }
            #pragma unroll
            for (int k = 0; k < 4; ++k) {
                float m = bf_max32(mx[k]);          // max over (c,ch) for this i
                float shift = 18.0f * (m - LN10);
                float p  = __expf(S[k] - shift);
                float ap = p * act_c;
                float A  = bf_sum32(ap);            // sum over c
                float invA = fast_rcp(A + EPSF);
                float re = ap * invA;
                float sk = A * invA;                // = sum_c re (reassoc)
                float an = a_in[k];
                rr[k] = re * an * fast_rcp(an * sk + EPSF);
            }
        } else {
            #pragma unroll
            for (int k = 0; k < 4; ++k) {
                float an = a_in[k];
                rr[k] = (1.0f / 32.0f) * an * fast_rcp(an + EPSF);
            }
        }

        // ---- combined partials: [Σrr, Σrr·v, Σrr·v²], xor32 pre-reduced ----
        {
            float* pp = &part[wv][c * PSTR];
            float prr = rr[0] + rr[1] + rr[2] + rr[3];
            float prs = prr + __shfl_xor(prr, 32);
            pp[0] = prs;                        // both halves write same value
            float s0 = cx * prr, s1v = cy * prr;
            s0  += __shfl_xor(s0, 32);
            s1v += __shfl_xor(s1v, 32);
            pp[1] = s0;  pp[19] = cx * s0;      // Σrr·cx², exact: cx*(Σrr·cx)
            pp[2] = s1v; pp[20] = cy * s1v;
            #pragma unroll
            for (int ch = 2; ch < CH; ++ch) {
                float s = 0.0f, s2 = 0.0f;
                #pragma unroll
                for (int k = 0; k < 4; ++k) {
                    float rv = rr[k] * v[k][ch - 2];
                    s  += rv;
                    s2 += rv * v[k][ch - 2];
                }
                s  += __shfl_xor(s, 32);
                s2 += __shfl_xor(s2, 32);
                pp[1 + ch]  = s;
                pp[19 + ch] = s2;
            }
        }
        __syncthreads();

        // ---- distributed reduce: rs, mu, sigma -> {mu,q} + base ----
        float r_sum;
        {
            const int base = c * PSTR;
            float rs = part[0][base] + part[1][base] + part[2][base] + part[3][base];
            r_sum = rs;
            float rsinv = fast_rcp(rs + EPSF);
            float s1 = rs * rsinv;
            float c2 = 2.0f - s1;
            for (int ch = ig; ch < CH; ch += 8) {
                int jm = base + 1 + ch, jv = base + 19 + ch;
                float mu_un = part[0][jm] + part[1][jm] + part[2][jm] + part[3][jm];
                float v2_un = part[0][jv] + part[1][jv] + part[2][jv] + part[3][jv];
                float mu  = mu_un * rsinv;
                float sig = fmaxf(v2_un * rsinv - mu * mu * c2, 0.0f) + EPSF;
                muq_s[c * 19 + ch]  = make_float2(mu, 0.5f * fast_rcp(sig));
                base_s[c * 19 + ch] = -0.5f * __logf(sig);
            }
        }
        __syncthreads();

        // ---- activation softmax over c (butterflies only) ----
        float logit;
        if (it == 2) {
            float cost = 0.0f;
            #pragma unroll
            for (int ch = 0; ch < CH; ++ch)
                cost += beta_v[c * CH + ch] - base_s[c * 19 + ch];  // +0.5*lsig
            logit = 0.03f * (beta_a[c] - cost * r_sum);   // ac_lambda = 0.01*3
        } else {
            logit = r_sum;
        }
        float mxl = bf_max32(logit);
        float ex  = __expf(logit - mxl);
        act_c = ex * fast_rcp(bf_sum32(ex));
    }

    // ---- fused spatial mean via atomics into d_out ----
    const float inv64 = 1.0f / 64.0f;
    const int b = n >> 6;
    if (t < CO) atomicAdd(&out[b * CO + t], act_c * inv64);   // t<32 -> c==t
    for (int e = t; e < CO * CH; e += 256) {
        int cc = e / CH, ch = e - cc * CH;
        atomicAdd(&out[OUT_ACT + b * (CO * CH) + e], muq_s[cc * 19 + ch].x * inv64);
    }
}

extern "C" void kernel_launch(void* const* d_in, const int* in_sizes, int n_in,
                              void* d_out, int out_size, void* d_ws, size_t ws_size,
                              hipStream_t stream) {
    const float* x         = (const float*)d_in[0];
    const float* w         = (const float*)d_in[1];
    const float* beta_v    = (const float*)d_in[2];
    const float* beta_a    = (const float*)d_in[3];
    const float* coord_add = (const float*)d_in[4];
    float* out = (float*)d_out;

    hipMemsetAsync(out, 0, (size_t)out_size * sizeof(float), stream);
    caps_em_kernel<<<dim3(NPOS), dim3(256), 0, stream>>>(
        x, w, beta_v, beta_a, coord_add, out);
}

// Round 7
// 84.183 us; speedup vs baseline: 1.1225x; 1.0746x over previous
//
#include <hip/hip_runtime.h>
#include <math.h>

// EM-routing class-capsule layer, MI355X (gfx950).
// R7: TWO positions per thread (grid 512, block 256) for 2x ILP — every
// dependency chain (S-accumulate -> butterfly -> expf -> butterfly -> rcp)
// now has an independent twin interleaved in the idle issue slots.
// Thread t: c = t&31, ig = t>>5 owns i = 4*ig+k for both positions
// n0 = 2*blockIdx, n1 = n0+1 (same batch row -> merged output atomics).
// Arithmetic byte-identical per position to the passing R6 kernel:
//   - bit-faithful E-step shift 18*(max_{c,ch} lp - ln10)  (R2 lesson)
//   - identical EPS placements, v_rcp_f32 divides, DPP+shfl butterflies
//   - sigma via exact identity  Σr1(v-mu)^2 = Σr1v^2 - mu^2*(2-s1)
// Partials packed as float2 (Σrv, Σrv·v) -> ~half the DS ops per round.

#define CI 32
#define CO 32
#define CH 18
#define NPOS 1024
#define OUT_ACT (16 * 32)     // 512 activation floats, then pose

constexpr float EPSF = 1e-9f;
constexpr float LN10 = 2.302585092994046f;

__device__ __forceinline__ float fast_rcp(float x) {
    return __builtin_amdgcn_rcpf(x);
}

template <int CTRL>
__device__ __forceinline__ float dppf(float x) {
    union { float f; int i; } u; u.f = x;
    u.i = __builtin_amdgcn_update_dpp(u.i, u.i, CTRL, 0xF, 0xF, true);
    return u.f;
}

// sum/max over each 32-lane group (lanes 0-31 and 32-63 independently).
__device__ __forceinline__ float bf_sum32(float x) {
    x += dppf<0xB1>(x);    // quad_perm xor1
    x += dppf<0x4E>(x);    // quad_perm xor2
    x += dppf<0x141>(x);   // row_half_mirror == xor4
    x += dppf<0x140>(x);   // row_mirror == xor8
    x += __shfl_xor(x, 16);
    return x;
}
__device__ __forceinline__ float bf_max32(float x) {
    x = fmaxf(x, dppf<0xB1>(x));
    x = fmaxf(x, dppf<0x4E>(x));
    x = fmaxf(x, dppf<0x141>(x));
    x = fmaxf(x, dppf<0x140>(x));
    x = fmaxf(x, __shfl_xor(x, 16));
    return x;
}

__global__ __launch_bounds__(256, 2) void caps_em_kernel(
    const float* __restrict__ x,
    const float* __restrict__ w,
    const float* __restrict__ beta_v,
    const float* __restrict__ beta_a,
    const float* __restrict__ coord_add,
    float* __restrict__ out)
{
    const int n0 = blockIdx.x * 2;
    const int t  = threadIdx.x;
    const int c  = t & 31;
    const int ig = t >> 5;            // 0..7
    const int wv = t >> 6;            // wave 0..3

    __shared__ float  pose[2][CI][16];
    __shared__ float  act_in[2][CI];
    __shared__ float  rs_part[2][4][CO];        // per-wave rs partials
    __shared__ float2 part2[2][4][CO * 19];     // (Σrv, Σrv·v) per ch, 19-pad
    __shared__ float2 muq_s[2][CO * 19];        // {mu, 0.5/sigma}
    __shared__ float  base_s[2][CO * 19];       // -0.5*log(sigma)

    // ---- load pose + activations for both positions (coalesced) ----
    const float* xrow = x + n0 * (CI * 17);
    for (int e = t; e < 2 * CI * 17; e += 256) {
        int p = e >= CI * 17;
        int idx = e - p * (CI * 17);
        int i = idx / 17, k = idx % 17;
        float val = xrow[e];
        if (k < 16) pose[p][i][k] = val;
        else        act_in[p][i]  = val;
    }
    float cxy[2][2];
    #pragma unroll
    for (int p = 0; p < 2; ++p) {
        cxy[p][0] = coord_add[((n0 + p) & 63) * 2 + 0];
        cxy[p][1] = coord_add[((n0 + p) & 63) * 2 + 1];
    }
    __syncthreads();

    // ---- votes: w-fragment loaded once per k, reused for both positions ----
    float v[2][4][16];
    #pragma unroll
    for (int k = 0; k < 4; ++k) {
        int i = ig * 4 + k;
        float wr[16];
        const float4* wp4 = (const float4*)(w + ((i * CO + c) << 4));
        #pragma unroll
        for (int q = 0; q < 4; ++q) {
            float4 wf = wp4[q];
            wr[q*4+0] = wf.x; wr[q*4+1] = wf.y; wr[q*4+2] = wf.z; wr[q*4+3] = wf.w;
        }
        #pragma unroll
        for (int p = 0; p < 2; ++p) {
            float pr[16];
            const float4* pp4 = (const float4*)pose[p][i];
            #pragma unroll
            for (int q = 0; q < 4; ++q) {
                float4 pf = pp4[q];
                pr[q*4+0] = pf.x; pr[q*4+1] = pf.y; pr[q*4+2] = pf.z; pr[q*4+3] = pf.w;
            }
            #pragma unroll
            for (int a = 0; a < 4; ++a) {
                #pragma unroll
                for (int d = 0; d < 4; ++d) {
                    float s = pr[a*4+0] * wr[0*4+d];
                    s += pr[a*4+1] * wr[1*4+d];
                    s += pr[a*4+2] * wr[2*4+d];
                    s += pr[a*4+3] * wr[3*4+d];
                    v[p][k][a*4+d] = s;
                }
            }
        }
    }

    float rr[2][4];
    float act_c[2] = {0.0f, 0.0f};
    float r_sum[2];

    for (int it = 0; it < 3; ++it) {
        if (it > 0) {
            // ---- E-step (exact reference shift), ch-outer, both positions ----
            float S[2][4], mx[2][4];
            #pragma unroll
            for (int p = 0; p < 2; ++p)
                #pragma unroll
                for (int k = 0; k < 4; ++k) { S[p][k] = 0.0f; mx[p][k] = -3.0e38f; }
            #pragma unroll
            for (int ch = 0; ch < CH; ++ch) {
                #pragma unroll
                for (int p = 0; p < 2; ++p) {
                    float2 mq = muq_s[p][c * 19 + ch];
                    float  bs = base_s[p][c * 19 + ch];
                    #pragma unroll
                    for (int k = 0; k < 4; ++k) {
                        float vv = (ch == 0) ? cxy[p][0]
                                 : ((ch == 1) ? cxy[p][1] : v[p][k][ch - 2]);
                        float d  = vv - mq.x;
                        float lp = bs - d * d * mq.y;
                        S[p][k] += lp;
                        mx[p][k] = fmaxf(mx[p][k], lp);
                    }
                }
            }
            #pragma unroll
            for (int k = 0; k < 4; ++k) {
                #pragma unroll
                for (int p = 0; p < 2; ++p) {
                    float m = bf_max32(mx[p][k]);      // max over (c,ch) for i
                    float shift = 18.0f * (m - LN10);
                    float pe = __expf(S[p][k] - shift);
                    float ap = pe * act_c[p];
                    float A  = bf_sum32(ap);           // sum over c
                    float invA = fast_rcp(A + EPSF);
                    float re = ap * invA;
                    float sk = A * invA;               // = sum_c re (reassoc)
                    float an = act_in[p][ig * 4 + k];
                    rr[p][k] = re * an * fast_rcp(an * sk + EPSF);
                }
            }
        } else {
            #pragma unroll
            for (int p = 0; p < 2; ++p)
                #pragma unroll
                for (int k = 0; k < 4; ++k) {
                    float an = act_in[p][ig * 4 + k];
                    rr[p][k] = (1.0f / 32.0f) * an * fast_rcp(an + EPSF);
                }
        }

        // ---- combined partials: rs + (Σrr·v, Σrr·v²) pairs, xor32-prereduced ----
        #pragma unroll
        for (int p = 0; p < 2; ++p) {
            float prr = rr[p][0] + rr[p][1] + rr[p][2] + rr[p][3];
            float prs = prr + __shfl_xor(prr, 32);
            rs_part[p][wv][c] = prs;                 // both halves: same value
            float2* pp = &part2[p][wv][c * 19];
            float cx = cxy[p][0], cy = cxy[p][1];
            float s0 = cx * prr, s1 = cy * prr;
            s0 += __shfl_xor(s0, 32);
            s1 += __shfl_xor(s1, 32);
            pp[0] = make_float2(s0, cx * s0);        // Σrr·cx² = cx·(Σrr·cx)
            pp[1] = make_float2(s1, cy * s1);
            #pragma unroll
            for (int ch = 2; ch < CH; ++ch) {
                float s = 0.0f, s2 = 0.0f;
                #pragma unroll
                for (int k = 0; k < 4; ++k) {
                    float rv = rr[p][k] * v[p][k][ch - 2];
                    s  += rv;
                    s2 += rv * v[p][k][ch - 2];
                }
                s  += __shfl_xor(s, 32);
                s2 += __shfl_xor(s2, 32);
                pp[ch] = make_float2(s, s2);
            }
        }
        __syncthreads();

        // ---- distributed reduce: rs, mu, sigma -> {mu,q} + base ----
        #pragma unroll
        for (int p = 0; p < 2; ++p) {
            float rs = rs_part[p][0][c] + rs_part[p][1][c]
                     + rs_part[p][2][c] + rs_part[p][3][c];
            r_sum[p] = rs;
            float rsinv = fast_rcp(rs + EPSF);
            float s1 = rs * rsinv;
            float c2 = 2.0f - s1;
            for (int ch = ig; ch < CH; ch += 8) {
                int j = c * 19 + ch;
                float2 a0 = part2[p][0][j], a1 = part2[p][1][j];
                float2 a2 = part2[p][2][j], a3 = part2[p][3][j];
                float mu_un = a0.x + a1.x + a2.x + a3.x;
                float v2_un = a0.y + a1.y + a2.y + a3.y;
                float mu  = mu_un * rsinv;
                float sig = fmaxf(v2_un * rsinv - mu * mu * c2, 0.0f) + EPSF;
                muq_s[p][j]  = make_float2(mu, 0.5f * fast_rcp(sig));
                base_s[p][j] = -0.5f * __logf(sig);
            }
        }
        __syncthreads();

        // ---- activation softmax over c (butterflies only) ----
        #pragma unroll
        for (int p = 0; p < 2; ++p) {
            float logit;
            if (it == 2) {
                float cost = 0.0f;
                #pragma unroll
                for (int ch = 0; ch < CH; ++ch)
                    cost += beta_v[c * CH + ch] - base_s[p][c * 19 + ch];
                logit = 0.03f * (beta_a[c] - cost * r_sum[p]);  // lambda=0.03
            } else {
                logit = r_sum[p];
            }
            float mxl = bf_max32(logit);
            float ex  = __expf(logit - mxl);
            act_c[p] = ex * fast_rcp(bf_sum32(ex));
        }
    }

    // ---- fused spatial mean: merged atomics (both positions, same b) ----
    const float inv64 = 1.0f / 64.0f;
    const int b = n0 >> 6;
    if (t < CO)
        atomicAdd(&out[b * CO + t], (act_c[0] + act_c[1]) * inv64);
    for (int e = t; e < CO * CH; e += 256) {
        int cc = e / CH, ch = e - cc * CH;
        float s = muq_s[0][cc * 19 + ch].x + muq_s[1][cc * 19 + ch].x;
        atomicAdd(&out[OUT_ACT + b * (CO * CH) + e], s * inv64);
    }
}

extern "C" void kernel_launch(void* const* d_in, const int* in_sizes, int n_in,
                              void* d_out, int out_size, void* d_ws, size_t ws_size,
                              hipStream_t stream) {
    const float* x         = (const float*)d_in[0];
    const float* w         = (const float*)d_in[1];
    const float* beta_v    = (const float*)d_in[2];
    const float* beta_a    = (const float*)d_in[3];
    const float* coord_add = (const float*)d_in[4];
    float* out = (float*)d_out;

    hipMemsetAsync(out, 0, (size_t)out_size * sizeof(float), stream);
    caps_em_kernel<<<dim3(NPOS / 2), dim3(256), 0, stream>>>(
        x, w, beta_v, beta_a, coord_add, out);
}